// Round 11
// baseline (267.244 us; speedup 1.0000x reference)
//
#include <hip/hip_runtime.h>

#define VOXELS   884736      // 96^3
#define OUT_CAM  0
#define OUT_PSE  23003136    // 2*13*VOXELS
#define OUT_MSK  24772608
#define OUT_LOG  26542080

// ws layout (floats)
#define WS_WT 0              // wt2[27][128][256]  (884736)
#define WS_P  884736         // P[54][2][128][64]  (884736)
#define WS_H1 1769472        // h1[2][128][8]      (2048)

typedef float  f32x4 __attribute__((ext_vector_type(4)));
typedef int    i32x4 __attribute__((ext_vector_type(4)));

// ---------------- CAM + pseudo + updated masks ----------------
// Rounds 1-10: five structures (serial, batch, pipelined, thread-split) all
// pin at 62 us / 2.5 TB/s -- depth/occupancy insensitive. Remaining axis:
// burst granularity at the memory controller. This variant: 8 floats/thread,
// ALL 28 loads issued as one pure-read burst (asm-pinned), pure-VALU
// processing, then ALL 30 stores as one pure-write burst. Per wave: 28KB
// read burst / 27KB write burst, 2KB contiguous per plane.
#define THRESH(t)                                   \
  t.x = (t.x > 0.2f) ? t.x : 0.0f;                  \
  t.y = (t.y > 0.2f) ? t.y : 0.0f;                  \
  t.z = (t.z > 0.2f) ? t.z : 0.0f;                  \
  t.w = (t.w > 0.2f) ? t.w : 0.0f;

__global__ __launch_bounds__(256) void k_cam(const float* __restrict__ feat,
                                             const int*   __restrict__ masks,
                                             float* __restrict__ out) {
  int T = blockIdx.x * 256 + threadIdx.x;   // < 221184
  int n = T >= 110592;
  int v = (T - n * 110592) * 8;             // 8 consecutive floats per thread
  const float scale = 1.0f / 884736.0f;

  const float* fp = feat + (size_t)(n * 14 + 1) * VOXELS + v;
  const int*   mp = masks + (size_t)n * VOXELS + v;

  // ---- pure read burst: 26 plane vec4s + 2 mask vec4s ----
  f32x4 fa[13], fb[13];
#pragma unroll
  for (int k = 0; k < 13; ++k) {
    fa[k] = *(const f32x4*)(fp + (size_t)k * VOXELS);
    fb[k] = *(const f32x4*)(fp + (size_t)k * VOXELS + 4);
  }
  i32x4 ma = *(const i32x4*)(mp);
  i32x4 mb = *(const i32x4*)(mp + 4);
  asm volatile("" : "+v"(fa[0]), "+v"(fa[1]), "+v"(fa[2]), "+v"(fa[3]),
                    "+v"(fa[4]), "+v"(fa[5]), "+v"(fa[6]), "+v"(fa[7]),
                    "+v"(fa[8]), "+v"(fa[9]), "+v"(fa[10]), "+v"(fa[11]),
                    "+v"(fa[12]));
  asm volatile("" : "+v"(fb[0]), "+v"(fb[1]), "+v"(fb[2]), "+v"(fb[3]),
                    "+v"(fb[4]), "+v"(fb[5]), "+v"(fb[6]), "+v"(fb[7]),
                    "+v"(fb[8]), "+v"(fb[9]), "+v"(fb[10]), "+v"(fb[11]),
                    "+v"(fb[12]));
  asm volatile("" : "+v"(ma), "+v"(mb));

  // ---- pure VALU: scale + threshold in place ----
#pragma unroll
  for (int k = 0; k < 13; ++k) {
    fa[k] *= scale; THRESH(fa[k]);
    fb[k] *= scale; THRESH(fb[k]);
  }

  // ---- pure write burst: 26 cam vec4 stores ----
  float* cb = out + OUT_CAM + (size_t)(n * 13) * VOXELS + v;
#pragma unroll
  for (int k = 0; k < 13; ++k) {
    __builtin_nontemporal_store(fa[k], (f32x4*)(cb + (size_t)k * VOXELS));
    __builtin_nontemporal_store(fb[k], (f32x4*)(cb + (size_t)k * VOXELS + 4));
  }

  // ---- argmax (first-max tie-break via strict >) ----
  f32x4 best_a = fa[0], best_b = fb[0];
  i32x4 bia = {0, 0, 0, 0}, bib = {0, 0, 0, 0};
#pragma unroll
  for (int k = 1; k < 13; ++k) {
    if (fa[k].x > best_a.x) { best_a.x = fa[k].x; bia.x = k; }
    if (fa[k].y > best_a.y) { best_a.y = fa[k].y; bia.y = k; }
    if (fa[k].z > best_a.z) { best_a.z = fa[k].z; bia.z = k; }
    if (fa[k].w > best_a.w) { best_a.w = fa[k].w; bia.w = k; }
    if (fb[k].x > best_b.x) { best_b.x = fb[k].x; bib.x = k; }
    if (fb[k].y > best_b.y) { best_b.y = fb[k].y; bib.y = k; }
    if (fb[k].z > best_b.z) { best_b.z = fb[k].z; bib.z = k; }
    if (fb[k].w > best_b.w) { best_b.w = fb[k].w; bib.w = k; }
  }
  f32x4 psa = {(float)bia.x, (float)bia.y, (float)bia.z, (float)bia.w};
  f32x4 psb = {(float)bib.x, (float)bib.y, (float)bib.z, (float)bib.w};
  f32x4 uma, umb;
  uma.x = (ma.x == 0) ? psa.x : (float)ma.x;
  uma.y = (ma.y == 0) ? psa.y : (float)ma.y;
  uma.z = (ma.z == 0) ? psa.z : (float)ma.z;
  uma.w = (ma.w == 0) ? psa.w : (float)ma.w;
  umb.x = (mb.x == 0) ? psb.x : (float)mb.x;
  umb.y = (mb.y == 0) ? psb.y : (float)mb.y;
  umb.z = (mb.z == 0) ? psb.z : (float)mb.z;
  umb.w = (mb.w == 0) ? psb.w : (float)mb.w;
  float* pp = out + OUT_PSE + (size_t)n * VOXELS + v;
  float* up = out + OUT_MSK + (size_t)n * VOXELS + v;
  __builtin_nontemporal_store(psa, (f32x4*)pp);
  __builtin_nontemporal_store(psb, (f32x4*)(pp + 4));
  __builtin_nontemporal_store(uma, (f32x4*)up);
  __builtin_nontemporal_store(umb, (f32x4*)(up + 4));
}

// ---------------- coalesced transpose: wt2[tap][oc][ic] = w1[oc][ic][tap] ----------------
__global__ __launch_bounds__(256) void k_trans(const float* __restrict__ w1,
                                               float* __restrict__ wt,
                                               float* __restrict__ logits) {
  __shared__ float s[6912];
  int r0 = blockIdx.x * 256;
  int tid = threadIdx.x;
  if (blockIdx.x == 0 && tid < 2) logits[tid] = 0.0f;
  for (int i = tid; i < 1728; i += 256)
    *(f32x4*)&s[i * 4] = *(const f32x4*)&w1[(size_t)r0 * 27 + i * 4];
  __syncthreads();
#pragma unroll
  for (int tap = 0; tap < 27; ++tap)
    wt[tap * 32768 + r0 + tid] = s[tid * 27 + tap];   // stride 27 coprime 32 banks
}

// ---------------- conv1 split-K partial GEMMs ----------------
#define WSTRIDE 68
__global__ __launch_bounds__(256) void k_conv1(const float* __restrict__ dom,
                                               const float* __restrict__ wt,
                                               float* __restrict__ P) {
  __shared__ float Wl[128 * WSTRIDE];
  __shared__ float Xl[128 * 64];
  int bx = blockIdx.x;
  int och = bx & 1;
  int ich = (bx >> 1) & 1;
  int rest = bx >> 2;              // 0..53
  int tap = rest % 27;
  int n = rest / 27;
  int kd = tap / 9 - 1, kh = (tap % 9) / 3 - 1, kw = tap % 3 - 1;
  int I0 = ich * 128, O0 = och * 64;
  int tid = threadIdx.x;

  for (int i = tid; i < 2048; i += 256) {
    int oc = i >> 5, k4 = (i & 31) << 2;
    f32x4 rd = *(const f32x4*)&wt[(size_t)(tap * 128 + O0 + oc) * 256 + I0 + k4];
    Wl[(k4 + 0) * WSTRIDE + oc] = rd.x;
    Wl[(k4 + 1) * WSTRIDE + oc] = rd.y;
    Wl[(k4 + 2) * WSTRIDE + oc] = rd.z;
    Wl[(k4 + 3) * WSTRIDE + oc] = rd.w;
  }
  for (int i = tid; i < 8192; i += 256) {
    int kk = i >> 6, pos = i & 63;
    int d = pos >> 4, h = (pos >> 2) & 3, w = pos & 3;
    int sd = d + kd, sh = h + kh, sw = w + kw;
    bool ok = ((unsigned)sd < 4u) && ((unsigned)sh < 4u) && ((unsigned)sw < 4u);
    Xl[i] = ok ? dom[((n * 256 + I0 + kk) << 6) + sd * 16 + sh * 4 + sw] : 0.0f;
  }
  __syncthreads();

  int to = tid >> 4, tp = tid & 15;
  f32x4 acc0 = {0, 0, 0, 0}, acc1 = {0, 0, 0, 0}, acc2 = {0, 0, 0, 0}, acc3 = {0, 0, 0, 0};
#pragma unroll 4
  for (int kk = 0; kk < 128; ++kk) {
    f32x4 a = *(f32x4*)&Wl[kk * WSTRIDE + to * 4];
    f32x4 b = *(f32x4*)&Xl[kk * 64 + tp * 4];
    acc0 += a.x * b;
    acc1 += a.y * b;
    acc2 += a.z * b;
    acc3 += a.w * b;
  }
  float* pb = P + (size_t)((tap * 2 + ich) * 2 + n) * 8192 + (O0 + to * 4) * 64 + tp * 4;
  *(f32x4*)(pb +   0) = acc0;
  *(f32x4*)(pb +  64) = acc1;
  *(f32x4*)(pb + 128) = acc2;
  *(f32x4*)(pb + 192) = acc3;
}

// ---------------- reduce partials + bias + maxpool2 + relu -> h1[2][128][8] ----------------
__global__ __launch_bounds__(256) void k_pool1(const float* __restrict__ P,
                                               const float* __restrict__ b1,
                                               float* __restrict__ h1) {
  __shared__ float s[256];
  int n = blockIdx.x >> 7, oc = blockIdx.x & 127;
  int tid = threadIdx.x, pos = tid & 63, sg = tid >> 6;
  float sum = 0.0f;
#pragma unroll
  for (int j = 0; j < 14; ++j) {
    int sl = sg + j * 4;
    if (sl < 54) sum += P[((size_t)(sl * 2 + n) * 128 + oc) * 64 + pos];
  }
  s[tid] = sum;
  __syncthreads();
  if (tid < 64) {
    float tot = b1[oc] + s[pos] + s[64 + pos] + s[128 + pos] + s[192 + pos];
    s[pos] = tot;
  }
  __syncthreads();
  if (tid < 8) {
    int pd = tid >> 2, ph = (tid >> 1) & 1, pw = tid & 1;
    float m = -3.402823466e38f;
#pragma unroll
    for (int dd = 0; dd < 2; ++dd)
#pragma unroll
      for (int hh = 0; hh < 2; ++hh)
#pragma unroll
        for (int ww = 0; ww < 2; ++ww)
          m = fmaxf(m, s[(pd * 2 + dd) * 16 + (ph * 2 + hh) * 4 + (pw * 2 + ww)]);
    h1[(n * 128 + oc) * 8 + tid] = fmaxf(m, 0.0f);
  }
}

// ---------------- conv2 + bias + maxpool2 + relu + linear (atomic) ----------------
__global__ __launch_bounds__(64) void k_conv2(const float* __restrict__ h1,
                                              const float* __restrict__ w2,
                                              const float* __restrict__ b2,
                                              const float* __restrict__ lw,
                                              const float* __restrict__ lb,
                                              float* __restrict__ logits) {
  __shared__ float hl[1024];
  __shared__ float wl[3456];
  __shared__ float red[64];
  int n = blockIdx.x >> 6, oc = blockIdx.x & 63;
  int tid = threadIdx.x;
  for (int i = tid; i < 1024; i += 64) hl[i] = h1[n * 1024 + i];
  for (int i = tid; i < 3456; i += 64) wl[i] = w2[oc * 3456 + i];
  __syncthreads();
  int p = tid & 7, g = tid >> 3;
  int d = p >> 2, h = (p >> 1) & 1, w = p & 1;
  float acc = 0.0f;
  for (int ic = g * 16; ic < g * 16 + 16; ++ic) {
#pragma unroll
    for (int a = 0; a < 2; ++a)
#pragma unroll
      for (int b = 0; b < 2; ++b)
#pragma unroll
        for (int c = 0; c < 2; ++c) {
          int tapi = (a - d + 1) * 9 + (b - h + 1) * 3 + (c - w + 1);
          acc += hl[ic * 8 + a * 4 + b * 2 + c] * wl[ic * 27 + tapi];
        }
  }
  red[tid] = acc;
  __syncthreads();
  if (tid == 0) {
    float mx = -3.402823466e38f;
#pragma unroll
    for (int pp = 0; pp < 8; ++pp) {
      float sv = b2[oc];
#pragma unroll
      for (int gg = 0; gg < 8; ++gg) sv += red[gg * 8 + pp];
      mx = fmaxf(mx, sv);
    }
    float h2v = fmaxf(mx, 0.0f);
    atomicAdd(&logits[n], h2v * lw[oc]);
    if (oc == 0) atomicAdd(&logits[n], lb[0]);
  }
}

extern "C" void kernel_launch(void* const* d_in, const int* in_sizes, int n_in,
                              void* d_out, int out_size, void* d_ws, size_t ws_size,
                              hipStream_t stream) {
  const float* feat  = (const float*)d_in[0];
  const int*   masks = (const int*)  d_in[1];
  const float* dom   = (const float*)d_in[2];
  const float* w1    = (const float*)d_in[3];
  const float* b1    = (const float*)d_in[4];
  const float* w2    = (const float*)d_in[5];
  const float* b2    = (const float*)d_in[6];
  const float* lw    = (const float*)d_in[7];
  const float* lb    = (const float*)d_in[8];
  float* out = (float*)d_out;
  float* ws  = (float*)d_ws;
  float* wt  = ws + WS_WT;
  float* P   = ws + WS_P;
  float* h1  = ws + WS_H1;
  float* logits = out + OUT_LOG;

  k_trans<<<128, 256, 0, stream>>>(w1, wt, logits);
  k_conv1<<<216, 256, 0, stream>>>(dom, wt, P);
  k_pool1<<<256, 256, 0, stream>>>(P, b1, h1);
  k_conv2<<<128, 64, 0, stream>>>(h1, w2, b2, lw, lb, logits);
  k_cam<<<864, 256, 0, stream>>>(feat, masks, out);
}

// Round 12
// 248.047 us; speedup vs baseline: 1.0774x; 1.0774x over previous
//
#include <hip/hip_runtime.h>

#define VOXELS   884736      // 96^3
#define OUT_CAM  0
#define OUT_PSE  23003136    // 2*13*VOXELS
#define OUT_MSK  24772608
#define OUT_LOG  26542080

// ws layout (floats)
#define WS_WT 0              // wt2[27][128][256]  (884736)
#define WS_P  884736         // P[54][2][128][64]  (884736)
#define WS_H1 1769472        // h1[2][128][8]      (2048)

typedef float  f32x4 __attribute__((ext_vector_type(4)));
typedef int    i32x4 __attribute__((ext_vector_type(4)));

// ---------------- pass A: contiguous scale+threshold (2-stream streaming) ----------------
// cam[flat] = thresh(feat[flat + (1+n)*V] * s).  flat covers 2*13 planes
// contiguously; feat side is contiguous within each n (planes 1..13).
// This is exactly the m13 float4-copy shape (6.3 TB/s reference). Normal
// stores keep cam L3-resident for pass B.
__global__ __launch_bounds__(256) void k_camA(const float* __restrict__ feat,
                                              float* __restrict__ out) {
  size_t i = ((size_t)blockIdx.x * 256 + threadIdx.x) * 4;   // < 23003136
  int n = i >= (size_t)13 * VOXELS;
  const float scale = 1.0f / 884736.0f;
  f32x4 f = *(const f32x4*)(feat + i + (size_t)(1 + n) * VOXELS);
  f *= scale;
  f.x = (f.x > 0.2f) ? f.x : 0.0f;
  f.y = (f.y > 0.2f) ? f.y : 0.0f;
  f.z = (f.z > 0.2f) ? f.z : 0.0f;
  f.w = (f.w > 0.2f) ? f.w : 0.0f;
  *(f32x4*)(out + OUT_CAM + i) = f;
}

// ---------------- pass B: argmax over cam planes (L3-warm) + mask update ----------------
__global__ __launch_bounds__(256) void k_camB(const int* __restrict__ masks,
                                              float* out) {
  int T = blockIdx.x * 256 + threadIdx.x;   // < 221184
  int n = T >= 110592;
  int v = (T - n * 110592) * 8;             // 8 floats per thread
  const float* cp = out + OUT_CAM + (size_t)(n * 13) * VOXELS + v;

  f32x4 best_a = *(const f32x4*)cp;
  f32x4 best_b = *(const f32x4*)(cp + 4);
  i32x4 bia = {0, 0, 0, 0}, bib = {0, 0, 0, 0};
#pragma unroll
  for (int k = 1; k < 13; ++k) {
    f32x4 ca = *(const f32x4*)(cp + (size_t)k * VOXELS);
    f32x4 cb = *(const f32x4*)(cp + (size_t)k * VOXELS + 4);
    if (ca.x > best_a.x) { best_a.x = ca.x; bia.x = k; }
    if (ca.y > best_a.y) { best_a.y = ca.y; bia.y = k; }
    if (ca.z > best_a.z) { best_a.z = ca.z; bia.z = k; }
    if (ca.w > best_a.w) { best_a.w = ca.w; bia.w = k; }
    if (cb.x > best_b.x) { best_b.x = cb.x; bib.x = k; }
    if (cb.y > best_b.y) { best_b.y = cb.y; bib.y = k; }
    if (cb.z > best_b.z) { best_b.z = cb.z; bib.z = k; }
    if (cb.w > best_b.w) { best_b.w = cb.w; bib.w = k; }
  }
  const int* mp = masks + (size_t)n * VOXELS + v;
  i32x4 ma = *(const i32x4*)mp;
  i32x4 mb = *(const i32x4*)(mp + 4);
  f32x4 psa = {(float)bia.x, (float)bia.y, (float)bia.z, (float)bia.w};
  f32x4 psb = {(float)bib.x, (float)bib.y, (float)bib.z, (float)bib.w};
  f32x4 uma, umb;
  uma.x = (ma.x == 0) ? psa.x : (float)ma.x;
  uma.y = (ma.y == 0) ? psa.y : (float)ma.y;
  uma.z = (ma.z == 0) ? psa.z : (float)ma.z;
  uma.w = (ma.w == 0) ? psa.w : (float)ma.w;
  umb.x = (mb.x == 0) ? psb.x : (float)mb.x;
  umb.y = (mb.y == 0) ? psb.y : (float)mb.y;
  umb.z = (mb.z == 0) ? psb.z : (float)mb.z;
  umb.w = (mb.w == 0) ? psb.w : (float)mb.w;
  float* pp = out + OUT_PSE + (size_t)n * VOXELS + v;
  float* up = out + OUT_MSK + (size_t)n * VOXELS + v;
  __builtin_nontemporal_store(psa, (f32x4*)pp);
  __builtin_nontemporal_store(psb, (f32x4*)(pp + 4));
  __builtin_nontemporal_store(uma, (f32x4*)up);
  __builtin_nontemporal_store(umb, (f32x4*)(up + 4));
}

// ---------------- coalesced transpose: wt2[tap][oc][ic] = w1[oc][ic][tap] ----------------
__global__ __launch_bounds__(256) void k_trans(const float* __restrict__ w1,
                                               float* __restrict__ wt,
                                               float* __restrict__ logits) {
  __shared__ float s[6912];
  int r0 = blockIdx.x * 256;
  int tid = threadIdx.x;
  if (blockIdx.x == 0 && tid < 2) logits[tid] = 0.0f;
  for (int i = tid; i < 1728; i += 256)
    *(f32x4*)&s[i * 4] = *(const f32x4*)&w1[(size_t)r0 * 27 + i * 4];
  __syncthreads();
#pragma unroll
  for (int tap = 0; tap < 27; ++tap)
    wt[tap * 32768 + r0 + tid] = s[tid * 27 + tap];   // stride 27 coprime 32 banks
}

// ---------------- conv1 split-K partial GEMMs ----------------
#define WSTRIDE 68
__global__ __launch_bounds__(256) void k_conv1(const float* __restrict__ dom,
                                               const float* __restrict__ wt,
                                               float* __restrict__ P) {
  __shared__ float Wl[128 * WSTRIDE];
  __shared__ float Xl[128 * 64];
  int bx = blockIdx.x;
  int och = bx & 1;
  int ich = (bx >> 1) & 1;
  int rest = bx >> 2;              // 0..53
  int tap = rest % 27;
  int n = rest / 27;
  int kd = tap / 9 - 1, kh = (tap % 9) / 3 - 1, kw = tap % 3 - 1;
  int I0 = ich * 128, O0 = och * 64;
  int tid = threadIdx.x;

  for (int i = tid; i < 2048; i += 256) {
    int oc = i >> 5, k4 = (i & 31) << 2;
    f32x4 rd = *(const f32x4*)&wt[(size_t)(tap * 128 + O0 + oc) * 256 + I0 + k4];
    Wl[(k4 + 0) * WSTRIDE + oc] = rd.x;
    Wl[(k4 + 1) * WSTRIDE + oc] = rd.y;
    Wl[(k4 + 2) * WSTRIDE + oc] = rd.z;
    Wl[(k4 + 3) * WSTRIDE + oc] = rd.w;
  }
  for (int i = tid; i < 8192; i += 256) {
    int kk = i >> 6, pos = i & 63;
    int d = pos >> 4, h = (pos >> 2) & 3, w = pos & 3;
    int sd = d + kd, sh = h + kh, sw = w + kw;
    bool ok = ((unsigned)sd < 4u) && ((unsigned)sh < 4u) && ((unsigned)sw < 4u);
    Xl[i] = ok ? dom[((n * 256 + I0 + kk) << 6) + sd * 16 + sh * 4 + sw] : 0.0f;
  }
  __syncthreads();

  int to = tid >> 4, tp = tid & 15;
  f32x4 acc0 = {0, 0, 0, 0}, acc1 = {0, 0, 0, 0}, acc2 = {0, 0, 0, 0}, acc3 = {0, 0, 0, 0};
#pragma unroll 4
  for (int kk = 0; kk < 128; ++kk) {
    f32x4 a = *(f32x4*)&Wl[kk * WSTRIDE + to * 4];
    f32x4 b = *(f32x4*)&Xl[kk * 64 + tp * 4];
    acc0 += a.x * b;
    acc1 += a.y * b;
    acc2 += a.z * b;
    acc3 += a.w * b;
  }
  float* pb = P + (size_t)((tap * 2 + ich) * 2 + n) * 8192 + (O0 + to * 4) * 64 + tp * 4;
  *(f32x4*)(pb +   0) = acc0;
  *(f32x4*)(pb +  64) = acc1;
  *(f32x4*)(pb + 128) = acc2;
  *(f32x4*)(pb + 192) = acc3;
}

// ---------------- reduce partials + bias + maxpool2 + relu -> h1[2][128][8] ----------------
__global__ __launch_bounds__(256) void k_pool1(const float* __restrict__ P,
                                               const float* __restrict__ b1,
                                               float* __restrict__ h1) {
  __shared__ float s[256];
  int n = blockIdx.x >> 7, oc = blockIdx.x & 127;
  int tid = threadIdx.x, pos = tid & 63, sg = tid >> 6;
  float sum = 0.0f;
#pragma unroll
  for (int j = 0; j < 14; ++j) {
    int sl = sg + j * 4;
    if (sl < 54) sum += P[((size_t)(sl * 2 + n) * 128 + oc) * 64 + pos];
  }
  s[tid] = sum;
  __syncthreads();
  if (tid < 64) {
    float tot = b1[oc] + s[pos] + s[64 + pos] + s[128 + pos] + s[192 + pos];
    s[pos] = tot;
  }
  __syncthreads();
  if (tid < 8) {
    int pd = tid >> 2, ph = (tid >> 1) & 1, pw = tid & 1;
    float m = -3.402823466e38f;
#pragma unroll
    for (int dd = 0; dd < 2; ++dd)
#pragma unroll
      for (int hh = 0; hh < 2; ++hh)
#pragma unroll
        for (int ww = 0; ww < 2; ++ww)
          m = fmaxf(m, s[(pd * 2 + dd) * 16 + (ph * 2 + hh) * 4 + (pw * 2 + ww)]);
    h1[(n * 128 + oc) * 8 + tid] = fmaxf(m, 0.0f);
  }
}

// ---------------- conv2 + bias + maxpool2 + relu + linear (atomic) ----------------
__global__ __launch_bounds__(64) void k_conv2(const float* __restrict__ h1,
                                              const float* __restrict__ w2,
                                              const float* __restrict__ b2,
                                              const float* __restrict__ lw,
                                              const float* __restrict__ lb,
                                              float* __restrict__ logits) {
  __shared__ float hl[1024];
  __shared__ float wl[3456];
  __shared__ float red[64];
  int n = blockIdx.x >> 6, oc = blockIdx.x & 63;
  int tid = threadIdx.x;
  for (int i = tid; i < 1024; i += 64) hl[i] = h1[n * 1024 + i];
  for (int i = tid; i < 3456; i += 64) wl[i] = w2[oc * 3456 + i];
  __syncthreads();
  int p = tid & 7, g = tid >> 3;
  int d = p >> 2, h = (p >> 1) & 1, w = p & 1;
  float acc = 0.0f;
  for (int ic = g * 16; ic < g * 16 + 16; ++ic) {
#pragma unroll
    for (int a = 0; a < 2; ++a)
#pragma unroll
      for (int b = 0; b < 2; ++b)
#pragma unroll
        for (int c = 0; c < 2; ++c) {
          int tapi = (a - d + 1) * 9 + (b - h + 1) * 3 + (c - w + 1);
          acc += hl[ic * 8 + a * 4 + b * 2 + c] * wl[ic * 27 + tapi];
        }
  }
  red[tid] = acc;
  __syncthreads();
  if (tid == 0) {
    float mx = -3.402823466e38f;
#pragma unroll
    for (int pp = 0; pp < 8; ++pp) {
      float sv = b2[oc];
#pragma unroll
      for (int gg = 0; gg < 8; ++gg) sv += red[gg * 8 + pp];
      mx = fmaxf(mx, sv);
    }
    float h2v = fmaxf(mx, 0.0f);
    atomicAdd(&logits[n], h2v * lw[oc]);
    if (oc == 0) atomicAdd(&logits[n], lb[0]);
  }
}

extern "C" void kernel_launch(void* const* d_in, const int* in_sizes, int n_in,
                              void* d_out, int out_size, void* d_ws, size_t ws_size,
                              hipStream_t stream) {
  const float* feat  = (const float*)d_in[0];
  const int*   masks = (const int*)  d_in[1];
  const float* dom   = (const float*)d_in[2];
  const float* w1    = (const float*)d_in[3];
  const float* b1    = (const float*)d_in[4];
  const float* w2    = (const float*)d_in[5];
  const float* b2    = (const float*)d_in[6];
  const float* lw    = (const float*)d_in[7];
  const float* lb    = (const float*)d_in[8];
  float* out = (float*)d_out;
  float* ws  = (float*)d_ws;
  float* wt  = ws + WS_WT;
  float* P   = ws + WS_P;
  float* h1  = ws + WS_H1;
  float* logits = out + OUT_LOG;

  k_trans<<<128, 256, 0, stream>>>(w1, wt, logits);
  k_conv1<<<216, 256, 0, stream>>>(dom, wt, P);
  k_pool1<<<256, 256, 0, stream>>>(P, b1, h1);
  k_conv2<<<128, 64, 0, stream>>>(h1, w2, b2, lw, lb, logits);
  k_camA<<<22464, 256, 0, stream>>>(feat, out);
  k_camB<<<864, 256, 0, stream>>>(masks, out);
}